// Round 11
// baseline (5566.645 us; speedup 1.0000x reference)
//
#include <hip/hip_runtime.h>
#include <hip/hip_bf16.h>

typedef __hip_bfloat16 bf16;
typedef __hip_bfloat162 bf162;

static constexpr int Bb = 512;
static constexpr int Hh = 512;
static constexpr int Ll = 64;
static constexpr int Vv = 1024;
static constexpr int MAXNB = 8;
static constexpr int Tt = 46;          // 2*(N-1)
static constexpr int TB = Tt * Bb;     // 23552, also PAD index
static constexpr int PADID = TB;
static constexpr int NROWS = TB + Bb;  // 24064
static constexpr int XPS = 3 * Hh;     // xproj row stride (bf16 elems)

__device__ __forceinline__ float b2f(bf16 v) { return __bfloat162float(v); }
__device__ __forceinline__ float sigm(float x) { return 1.f / (1.f + __expf(-x)); }

// dtype-adaptive scalar load
template <bool F32>
__device__ __forceinline__ float ldv(const void* p, long i) {
  if (F32) return ((const float*)p)[i];
  return __bfloat162float(((const bf16*)p)[i]);
}
// dtype-adaptive paired load at even element index i (adjacent elements)
template <bool F32>
__device__ __forceinline__ float2 ldv2(const void* p, long i) {
  if (F32) {
    const float* f = (const float*)p;
    return make_float2(f[i], f[i + 1]);
  }
  bf162 v = ((const bf162*)p)[i >> 1];
  return make_float2(__bfloat162float(v.x), __bfloat162float(v.y));
}
__device__ __forceinline__ float2 ldh2(const bf16* p, long i) {  // hbuf (always bf16)
  bf162 v = ((const bf162*)p)[i >> 1];
  return make_float2(__bfloat162float(v.x), __bfloat162float(v.y));
}

// ---------------------------------------------------------------------------
// dtype probe
// ---------------------------------------------------------------------------
__global__ void detect_kernel(const unsigned short* __restrict__ embu,
                              int* __restrict__ flag) {
  const long n = (long)Vv * Hh;
  int bad = 0;
  for (long i = blockIdx.x * 256 + threadIdx.x; i < n; i += 256L * 64) {
    unsigned short u = embu[i];
    if ((u & 0x7F80u) == 0x7F80u) bad = 1;
  }
  if (bad) atomicOr(flag, 1);
}

// ---------------------------------------------------------------------------
// xproj[v] = [emb[v]@Wz[:H]+bz | emb[v]@Wr+br | emb[v]@Wh[:H]+bh], bf16 out.
// ---------------------------------------------------------------------------
template <bool F32>
__device__ void xproj_body(const void* emb, const void* Wz, const void* bz,
                           const void* Wr, const void* br, const void* Wh,
                           const void* bh, bf16* xproj, float* xe) {
  const int v = blockIdx.x, k = threadIdx.x;
  xe[k] = ldv<F32>(emb, (long)v * Hh + k);
  __syncthreads();
  float z = ldv<F32>(bz, k);
  float r = ldv<F32>(br, k);
  float h = ldv<F32>(bh, k);
  for (int i = 0; i < Hh; ++i) {
    float a = xe[i];
    z += a * ldv<F32>(Wz, (long)i * Hh + k);
    r += a * ldv<F32>(Wr, (long)i * Hh + k);
    h += a * ldv<F32>(Wh, (long)i * Hh + k);
  }
  bf16* xp = xproj + (long)v * XPS;
  xp[k]          = __float2bfloat16(z);
  xp[Hh + k]     = __float2bfloat16(r);
  xp[2 * Hh + k] = __float2bfloat16(h);
}

__global__ __launch_bounds__(512) void xproj_kernel(
    const void* emb, const void* Wz, const void* bz, const void* Wr,
    const void* br, const void* Wh, const void* bh, bf16* xproj,
    const int* __restrict__ flag) {
  __shared__ float xe[Hh];
  if (*flag)
    xproj_body<true>(emb, Wz, bz, Wr, br, Wh, bh, xproj, xe);
  else
    xproj_body<false>(emb, Wz, bz, Wr, br, Wh, bh, xproj, xe);
}

// ---------------------------------------------------------------------------
// Per-row sum_g: one Ur stream (bf16x2, 8-deep batched) feeding NV neighbors.
// ---------------------------------------------------------------------------
template <bool F32, int NV>
__device__ __forceinline__ void sumg2(const void* Ur, int c0, const float* hnc,
                                      float pr0, float pr1, float& g0,
                                      float& g1) {
  float a0[NV], a1[NV];
#pragma unroll
  for (int j = 0; j < NV; ++j) { a0[j] = pr0; a1[j] = pr1; }
  for (int i = 0; i < Hh; i += 8) {
    float2 uv[8];
#pragma unroll
    for (int u = 0; u < 8; ++u) uv[u] = ldv2<F32>(Ur, (long)(i + u) * Hh + c0);
#pragma unroll
    for (int u = 0; u < 8; ++u) {
#pragma unroll
      for (int j = 0; j < NV; ++j) {
        float hv = hnc[j * Hh + i + u];
        a0[j] += hv * uv[u].x;
        a1[j] += hv * uv[u].y;
      }
    }
  }
#pragma unroll
  for (int j = 0; j < NV; ++j) {
    g0 += sigm(a0[j]) * hnc[j * Hh + c0];
    g1 += sigm(a1[j]) * hnc[j * Hh + c0 + 1];
  }
}

// ---------------------------------------------------------------------------
// GRU scan step (xproj path): 2 rows/block, 512 threads.
// Threads 0-255 -> row b0, 256-511 -> row b1; each thread owns column pair
// c0=2*(tid&255). All weight streams: bf16x2 loads, 8-deep batched (2 KB
// in flight per wave). Both halves issue identical weight addresses.
// ---------------------------------------------------------------------------
template <bool F32>
__device__ void gru_body_xp(int t, const int* wid, const int* hni,
                            const bf16* xproj, const void* Wz, const void* Ur,
                            const void* Wh, bf16* hbuf, float* sh, float* sg,
                            float* hnc, int* ids, int* nvp) {
  const int tid = threadIdx.x;
  const int h = tid >> 8;        // row-half 0/1
  const int l = tid & 255;
  const int c0 = 2 * l;
  const int b = blockIdx.x * 2 + h;

  if (tid < 2 * MAXNB)
    ids[tid] = hni[((long)t * Bb + blockIdx.x * 2 + (tid >> 3)) * MAXNB + (tid & 7)];
  __syncthreads();
  if (l == 0) {  // tid 0 and 256
    int n = 0;
    while (n < MAXNB && ids[h * MAXNB + n] != PADID) ++n;
    nvp[h] = n;
  }
  __syncthreads();
  const int nv = nvp[h];           // wave-uniform
  const int* myids = ids + h * MAXNB;
  float* myhnc = hnc + h * MAXNB * Hh;
  float* mysh = sh + h * Hh;
  float* mysg = sg + h * Hh;

  const int w = wid[t * Bb + b];
  const bf16* xp = xproj + (long)w * XPS;

  float s0 = 0.f, s1 = 0.f;
  for (int j = 0; j < nv; ++j) {   // wave-uniform bound
    float2 hv = ldh2(hbuf, (long)myids[j] * Hh + c0);
    myhnc[j * Hh + c0] = hv.x;
    myhnc[j * Hh + c0 + 1] = hv.y;
    s0 += hv.x; s1 += hv.y;
  }
  mysh[c0] = s0; mysh[c0 + 1] = s1;
  __syncthreads();

  // z pre-activation: xz + sum_h @ Wz[H:], 8-deep bf16x2
  float2 xz = ldh2(xp, c0);
  float z0 = xz.x, z1 = xz.y;
  for (int i = 0; i < Hh; i += 8) {
    float2 wv[8];
#pragma unroll
    for (int u = 0; u < 8; ++u) wv[u] = ldv2<F32>(Wz, (long)(Hh + i + u) * Hh + c0);
#pragma unroll
    for (int u = 0; u < 8; ++u) {
      float a = mysh[i + u];
      z0 += a * wv[u].x; z1 += a * wv[u].y;
    }
  }

  // r gate + sum_g: single 8-deep Ur stream
  float2 xr = ldh2(xp, Hh + c0);
  float g0 = 0.f, g1 = 0.f;
  switch (nv) {
    case 1: sumg2<F32, 1>(Ur, c0, myhnc, xr.x, xr.y, g0, g1); break;
    case 2: sumg2<F32, 2>(Ur, c0, myhnc, xr.x, xr.y, g0, g1); break;
    case 3: sumg2<F32, 3>(Ur, c0, myhnc, xr.x, xr.y, g0, g1); break;
    case 4: sumg2<F32, 4>(Ur, c0, myhnc, xr.x, xr.y, g0, g1); break;
    case 5: sumg2<F32, 5>(Ur, c0, myhnc, xr.x, xr.y, g0, g1); break;
    case 6: sumg2<F32, 6>(Ur, c0, myhnc, xr.x, xr.y, g0, g1); break;
    case 7: sumg2<F32, 7>(Ur, c0, myhnc, xr.x, xr.y, g0, g1); break;
    case 8: sumg2<F32, 8>(Ur, c0, myhnc, xr.x, xr.y, g0, g1); break;
    default: break;  // nv==0
  }
  mysg[c0] = g0; mysg[c0 + 1] = g1;
  __syncthreads();

  // h_tilde = tanh(xh + sum_g @ Wh[H:]), 8-deep bf16x2
  float2 xh = ldh2(xp, 2 * Hh + c0);
  float h0 = xh.x, h1 = xh.y;
  for (int i = 0; i < Hh; i += 8) {
    float2 wv[8];
#pragma unroll
    for (int u = 0; u < 8; ++u) wv[u] = ldv2<F32>(Wh, (long)(Hh + i + u) * Hh + c0);
#pragma unroll
    for (int u = 0; u < 8; ++u) {
      float a = mysg[i + u];
      h0 += a * wv[u].x; h1 += a * wv[u].y;
    }
  }

  float z = sigm(z0);
  float o0 = (1.f - z) * s0 + z * tanhf(h0);
  z = sigm(z1);
  float o1 = (1.f - z) * s1 + z * tanhf(h1);
  bf162 ov;
  ov.x = __float2bfloat16(o0);
  ov.y = __float2bfloat16(o1);
  ((bf162*)hbuf)[(((long)t * Bb + b) * Hh + c0) >> 1] = ov;
}

__global__ __launch_bounds__(512, 2) void gru_step_xp(
    int t, const int* __restrict__ wid, const int* __restrict__ hni,
    const bf16* xproj, const void* Wz, const void* Ur, const void* Wh,
    bf16* hbuf, const int* __restrict__ flag) {
  __shared__ float sh[2 * Hh];
  __shared__ float sg[2 * Hh];
  __shared__ float hnc[2 * MAXNB * Hh];
  __shared__ int   ids[2 * MAXNB];
  __shared__ int   nvp[2];
  if (*flag)
    gru_body_xp<true>(t, wid, hni, xproj, Wz, Ur, Wh, hbuf, sh, sg, hnc, ids, nvp);
  else
    gru_body_xp<false>(t, wid, hni, xproj, Wz, Ur, Wh, hbuf, sh, sg, hnc, ids, nvp);
}

// ---------------------------------------------------------------------------
// Stop head: rows = [emb[w] | sum(hbuf[oni]) | mol_vec] (24064 x 1088)
// Cols per thread: 2t, 2t+1 -> one bf16x2 U-load serves both. 4-wide batch.
// ---------------------------------------------------------------------------
template <bool F32>
__device__ void stop_body(const void* mol_vec, const int* wid,
                          const int* dirs, const int* oni,
                          const int* root_wid, const int* roni,
                          const void* emb, const void* U, const void* bU,
                          const void* Us, const void* bs, const bf16* hbuf,
                          float* accum,
                          float (*srow)[2 * Hh + Ll], float (*red)[256],
                          float* fin) {
  const int tid = threadIdx.x;
  const int i0 = blockIdx.x * 8;
  const int K = 2 * Hh + Ll;   // 1088
  const int K2 = K / 2;        // 544
  const int c0 = 2 * tid;

  for (int r = 0; r < 8; ++r) {
    int i = i0 + r;
    int w, b;
    const int* ids;
    if (i < TB) { w = wid[i]; b = i % Bb; ids = &oni[(long)i * MAXNB]; }
    else { int j = i - TB; w = root_wid[j]; b = j; ids = &roni[(long)j * MAXNB]; }
    for (int c2 = tid; c2 < K2; c2 += 256) {
      int c = 2 * c2;  // pairs never straddle region boundaries (0/512/1024)
      float v0, v1;
      if (c < Hh) {
        float2 e = ldv2<F32>(emb, (long)w * Hh + c);
        v0 = e.x; v1 = e.y;
      } else if (c < 2 * Hh) {
        int cc = c - Hh;
        v0 = 0.f; v1 = 0.f;
        for (int j = 0; j < MAXNB; ++j) {
          float2 hv = ldh2(hbuf, (long)ids[j] * Hh + cc);
          v0 += hv.x; v1 += hv.y;
        }
      } else {
        float2 m = ldv2<F32>(mol_vec, (long)b * Ll + (c - 2 * Hh));
        v0 = m.x; v1 = m.y;
      }
      srow[r][c] = v0;
      srow[r][c + 1] = v1;
    }
  }
  __syncthreads();

  float acc[8][2] = {};
  for (int kk = 0; kk < K; kk += 4) {
    float2 uv[4];
#pragma unroll
    for (int u = 0; u < 4; ++u) uv[u] = ldv2<F32>(U, (long)(kk + u) * Hh + c0);
#pragma unroll
    for (int u = 0; u < 4; ++u) {
#pragma unroll
      for (int r = 0; r < 8; ++r) {
        float a = srow[r][kk + u];
        acc[r][0] += a * uv[u].x; acc[r][1] += a * uv[u].y;
      }
    }
  }
  float2 bUv = ldv2<F32>(bU, c0);
  float2 usv = ldv2<F32>(Us, c0);
  __syncthreads();
#pragma unroll
  for (int r = 0; r < 8; ++r)
    red[r][tid] = fmaxf(acc[r][0] + bUv.x, 0.f) * usv.x +
                  fmaxf(acc[r][1] + bUv.y, 0.f) * usv.y;
  __syncthreads();
  for (int off = 128; off; off >>= 1) {
    if (tid < off) {
#pragma unroll
      for (int r = 0; r < 8; ++r) red[r][tid] += red[r][tid + off];
    }
    __syncthreads();
  }
  if (tid < 8) {
    int i = i0 + tid;
    float s = red[tid][0] + ldv<F32>(bs, 0);
    float tgt = (i < TB) ? (float)dirs[i] : 0.f;
    float loss = fmaxf(s, 0.f) - s * tgt + log1pf(expf(-fabsf(s)));
    float ok = ((s >= 0.5f) == (tgt > 0.5f)) ? 1.f : 0.f;
    fin[tid] = loss; fin[8 + tid] = ok;
  }
  __syncthreads();
  if (tid == 0) {
    float ls = 0.f, oks = 0.f;
    for (int r = 0; r < 8; ++r) { ls += fin[r]; oks += fin[8 + r]; }
    atomicAdd(&accum[0], ls);
    atomicAdd(&accum[1], oks);
  }
}

__global__ __launch_bounds__(256) void stop_kernel(
    const void* mol_vec, const int* __restrict__ wid,
    const int* __restrict__ dirs, const int* __restrict__ oni,
    const int* __restrict__ root_wid, const int* __restrict__ roni,
    const void* emb, const void* U, const void* bU, const void* Us,
    const void* bs, const bf16* hbuf, float* accum,
    const int* __restrict__ flag) {
  __shared__ float srow[8][2 * Hh + Ll];
  __shared__ float red[8][256];
  __shared__ float fin[16];
  if (*flag)
    stop_body<true>(mol_vec, wid, dirs, oni, root_wid, roni, emb, U, bU, Us,
                    bs, hbuf, accum, srow, red, fin);
  else
    stop_body<false>(mol_vec, wid, dirs, oni, root_wid, roni, emb, U, bU, Us,
                     bs, hbuf, accum, srow, red, fin);
}

// ---------------------------------------------------------------------------
// Pred head: hid = relu([pred_h | mv] @ W + bW); logits = hid @ Wo + bo
// GEMM1 cols 2t,2t+1 (bf16x2); GEMM2 cols 4t..4t+3 (2x bf16x2).
// ---------------------------------------------------------------------------
template <bool F32>
__device__ void pred_body(const void* mol_vec, const int* y_wid,
                          const int* dirs, const int* root_wid, const void* W,
                          const void* bW, const void* Wo, const void* bo,
                          const bf16* hbuf, float* accum,
                          float (*srow)[Hh + Ll], float (*hid)[Hh],
                          float* rv, int* ri, float* sb) {
  const int tid = threadIdx.x;
  const int i0 = blockIdx.x * 8;
  const int K1 = Hh + Ll;   // 576
  const int K12 = K1 / 2;   // 288
  const int c0 = 2 * tid;

  for (int r = 0; r < 8; ++r) {
    int i = i0 + r;
    int b = (i < Bb) ? i : (i - Bb) % Bb;
    for (int c2 = tid; c2 < K12; c2 += 256) {
      int c = 2 * c2;  // pairs never straddle the 512 boundary
      float v0, v1;
      if (c < Hh) {
        if (i < Bb) { v0 = 0.f; v1 = 0.f; }
        else {
          float2 hv = ldh2(hbuf, (long)(i - Bb) * Hh + c);
          v0 = hv.x; v1 = hv.y;
        }
      } else {
        float2 m = ldv2<F32>(mol_vec, (long)b * Ll + (c - Hh));
        v0 = m.x; v1 = m.y;
      }
      srow[r][c] = v0;
      srow[r][c + 1] = v1;
    }
  }
  __syncthreads();

  float acc[8][2] = {};
  for (int kk = 0; kk < K1; kk += 4) {
    float2 wv[4];
#pragma unroll
    for (int u = 0; u < 4; ++u) wv[u] = ldv2<F32>(W, (long)(kk + u) * Hh + c0);
#pragma unroll
    for (int u = 0; u < 4; ++u) {
#pragma unroll
      for (int r = 0; r < 8; ++r) {
        float a = srow[r][kk + u];
        acc[r][0] += a * wv[u].x; acc[r][1] += a * wv[u].y;
      }
    }
  }
  float2 bWv = ldv2<F32>(bW, c0);
#pragma unroll
  for (int r = 0; r < 8; ++r) {
    hid[r][c0] = fmaxf(acc[r][0] + bWv.x, 0.f);
    hid[r][c0 + 1] = fmaxf(acc[r][1] + bWv.y, 0.f);
  }
  __syncthreads();

  const int v0c = 4 * tid;
  float lg[8][4] = {};
  for (int kk = 0; kk < Hh; kk += 2) {
    float2 wa[2][2];
#pragma unroll
    for (int u = 0; u < 2; ++u) {
      wa[u][0] = ldv2<F32>(Wo, (long)(kk + u) * Vv + v0c);
      wa[u][1] = ldv2<F32>(Wo, (long)(kk + u) * Vv + v0c + 2);
    }
#pragma unroll
    for (int u = 0; u < 2; ++u) {
#pragma unroll
      for (int r = 0; r < 8; ++r) {
        float a = hid[r][kk + u];
        lg[r][0] += a * wa[u][0].x; lg[r][1] += a * wa[u][0].y;
        lg[r][2] += a * wa[u][1].x; lg[r][3] += a * wa[u][1].y;
      }
    }
  }
  float2 bov0 = ldv2<F32>(bo, v0c);
  float2 bov1 = ldv2<F32>(bo, v0c + 2);

  float plloss = 0.f, pnum = 0.f, pmask = 0.f;  // live in thread 0
  for (int r = 0; r < 8; ++r) {
    int i = i0 + r;
    int tgt = (i < Bb) ? root_wid[i] : y_wid[i - Bb];
    float msk = (i < Bb) ? 1.f : (float)dirs[i - Bb];
    float v0 = lg[r][0] + bov0.x, v1 = lg[r][1] + bov0.y;
    float v2 = lg[r][2] + bov1.x, v3 = lg[r][3] + bov1.y;

    // per-thread first-max over ascending candidate indices
    float bm = v0; int bi = v0c;
    if (v1 > bm) { bm = v1; bi = v0c + 1; }
    if (v2 > bm) { bm = v2; bi = v0c + 2; }
    if (v3 > bm) { bm = v3; bi = v0c + 3; }
    rv[tid] = bm; ri[tid] = bi;
    if ((tgt >> 2) == tid) {
      int cc = tgt & 3;
      sb[0] = (cc == 0) ? v0 : (cc == 1) ? v1 : (cc == 2) ? v2 : v3;
    }
    __syncthreads();
    for (int off = 128; off; off >>= 1) {
      if (tid < off) {
        float o = rv[tid + off]; int oi = ri[tid + off];
        if (o > rv[tid] || (o == rv[tid] && oi < ri[tid])) { rv[tid] = o; ri[tid] = oi; }
      }
      __syncthreads();
    }
    float m = rv[0];
    int am = ri[0];
    __syncthreads();
    rv[tid] = __expf(v0 - m) + __expf(v1 - m) + __expf(v2 - m) + __expf(v3 - m);
    __syncthreads();
    for (int off = 128; off; off >>= 1) {
      if (tid < off) rv[tid] += rv[tid + off];
      __syncthreads();
    }
    if (tid == 0) {
      float lse = m + __logf(rv[0]);
      float ce = lse - sb[0];
      plloss += ce * msk;
      pnum += (am == tgt) ? msk : 0.f;
      pmask += msk;
    }
    __syncthreads();
  }
  if (tid == 0) {
    atomicAdd(&accum[2], plloss);
    atomicAdd(&accum[3], pnum);
    atomicAdd(&accum[4], pmask);
  }
}

__global__ __launch_bounds__(256) void pred_kernel(
    const void* mol_vec, const int* __restrict__ y_wid,
    const int* __restrict__ dirs, const int* __restrict__ root_wid,
    const void* W, const void* bW, const void* Wo, const void* bo,
    const bf16* hbuf, float* accum, const int* __restrict__ flag) {
  __shared__ float srow[8][Hh + Ll];
  __shared__ float hid[8][Hh];
  __shared__ float rv[256];
  __shared__ int   ri[256];
  __shared__ float sb[2];
  if (*flag)
    pred_body<true>(mol_vec, y_wid, dirs, root_wid, W, bW, Wo, bo, hbuf,
                    accum, srow, hid, rv, ri, sb);
  else
    pred_body<false>(mol_vec, y_wid, dirs, root_wid, W, bW, Wo, bo, hbuf,
                     accum, srow, hid, rv, ri, sb);
}

__global__ void finalize_kernel(const float* __restrict__ accum,
                                const int* __restrict__ flag, void* out) {
  if (threadIdx.x == 0 && blockIdx.x == 0) {
    float o0 = accum[2] / (float)Bb;      // pred_loss
    float o1 = accum[0] / (float)Bb;      // stop_loss
    float o2 = accum[3] / accum[4];       // pred_acc
    float o3 = accum[1] / (float)NROWS;   // stop_acc
    if (*flag) {
      float* o = (float*)out;
      o[0] = o0; o[1] = o1; o[2] = o2; o[3] = o3;
    } else {
      bf16* o = (bf16*)out;
      o[0] = __float2bfloat16(o0); o[1] = __float2bfloat16(o1);
      o[2] = __float2bfloat16(o2); o[3] = __float2bfloat16(o3);
    }
  }
}

extern "C" void kernel_launch(void* const* d_in, const int* in_sizes, int n_in,
                              void* d_out, int out_size, void* d_ws, size_t ws_size,
                              hipStream_t stream) {
  const void* mol_vec  = d_in[0];
  const int*  wid      = (const int*)d_in[1];
  const int*  y_wid    = (const int*)d_in[2];
  const int*  dirs     = (const int*)d_in[3];
  const int*  hni      = (const int*)d_in[4];
  const int*  oni      = (const int*)d_in[5];
  const int*  root_wid = (const int*)d_in[6];
  const int*  roni     = (const int*)d_in[7];
  const void* emb      = d_in[8];
  const void* Wz       = d_in[9];
  const void* bz       = d_in[10];
  const void* Wr       = d_in[11];
  const void* br       = d_in[12];
  const void* Ur       = d_in[13];
  const void* Wh       = d_in[14];
  const void* bh       = d_in[15];
  const void* W        = d_in[16];
  const void* bW       = d_in[17];
  const void* U        = d_in[18];
  const void* bU       = d_in[19];
  const void* Wo       = d_in[20];
  const void* bo       = d_in[21];
  const void* Us       = d_in[22];
  const void* bs       = d_in[23];

  // ws layout: [accum 8f][flag 1i][pad->64B][hbuf (TB+1)*Hh bf16][xproj V*XPS bf16]
  float* accum = (float*)d_ws;
  int*   flag  = (int*)d_ws + 8;
  bf16*  hbuf  = (bf16*)((char*)d_ws + 64);
  bf16*  xproj = hbuf + (long)(TB + 1) * Hh;

  hipMemsetAsync(d_ws, 0, 64, stream);                                   // accum+flag
  hipMemsetAsync(hbuf + (long)TB * Hh, 0, Hh * sizeof(bf16), stream);    // PAD row

  detect_kernel<<<64, 256, 0, stream>>>((const unsigned short*)emb, flag);

  xproj_kernel<<<Vv, 512, 0, stream>>>(emb, Wz, bz, Wr, br, Wh, bh, xproj, flag);
  for (int t = 0; t < Tt; ++t) {
    gru_step_xp<<<Bb / 2, 512, 0, stream>>>(t, wid, hni, xproj, Wz, Ur, Wh,
                                            hbuf, flag);
  }
  stop_kernel<<<NROWS / 8, 256, 0, stream>>>(mol_vec, wid, dirs, oni, root_wid,
                                             roni, emb, U, bU, Us, bs, hbuf,
                                             accum, flag);
  pred_kernel<<<NROWS / 8, 256, 0, stream>>>(mol_vec, y_wid, dirs, root_wid, W,
                                             bW, Wo, bo, hbuf, accum, flag);
  finalize_kernel<<<1, 64, 0, stream>>>(accum, flag, d_out);
}

// Round 12
// 4137.933 us; speedup vs baseline: 1.3453x; 1.3453x over previous
//
#include <hip/hip_runtime.h>
#include <hip/hip_bf16.h>

typedef __hip_bfloat16 bf16;

static constexpr int Bb = 512;
static constexpr int Hh = 512;
static constexpr int Ll = 64;
static constexpr int Vv = 1024;
static constexpr int MAXNB = 8;
static constexpr int Tt = 46;          // 2*(N-1)
static constexpr int TB = Tt * Bb;     // 23552, also PAD index
static constexpr int PADID = TB;
static constexpr int NROWS = TB + Bb;  // 24064
static constexpr int XPS = 3 * Hh;     // xproj row stride (bf16 elems)

__device__ __forceinline__ float b2f(bf16 v) { return __bfloat162float(v); }
__device__ __forceinline__ float sigm(float x) { return 1.f / (1.f + __expf(-x)); }

// dtype-adaptive scalar load
template <bool F32>
__device__ __forceinline__ float ldv(const void* p, long i) {
  if (F32) return ((const float*)p)[i];
  return __bfloat162float(((const bf16*)p)[i]);
}

// dtype-adaptive 4-wide load at 4-aligned element index (ushort4 = 8B aligned,
// float4 = 16B aligned; both hold on all call sites: c0 = 4*cg).
template <bool F32>
__device__ __forceinline__ void ld4(const void* p, long i, float* o) {
  if (F32) {
    float4 v = *(const float4*)((const float*)p + i);
    o[0] = v.x; o[1] = v.y; o[2] = v.z; o[3] = v.w;
  } else {
    ushort4 v = *(const ushort4*)((const bf16*)p + i);
    o[0] = __uint_as_float((unsigned)v.x << 16);
    o[1] = __uint_as_float((unsigned)v.y << 16);
    o[2] = __uint_as_float((unsigned)v.z << 16);
    o[3] = __uint_as_float((unsigned)v.w << 16);
  }
}
__device__ __forceinline__ void ldh4(const bf16* p, long i, float* o) {
  ushort4 v = *(const ushort4*)(p + i);
  o[0] = __uint_as_float((unsigned)v.x << 16);
  o[1] = __uint_as_float((unsigned)v.y << 16);
  o[2] = __uint_as_float((unsigned)v.z << 16);
  o[3] = __uint_as_float((unsigned)v.w << 16);
}

// ---------------------------------------------------------------------------
// dtype probe
// ---------------------------------------------------------------------------
__global__ void detect_kernel(const unsigned short* __restrict__ embu,
                              int* __restrict__ flag) {
  const long n = (long)Vv * Hh;
  int bad = 0;
  for (long i = blockIdx.x * 256 + threadIdx.x; i < n; i += 256L * 64) {
    unsigned short u = embu[i];
    if ((u & 0x7F80u) == 0x7F80u) bad = 1;
  }
  if (bad) atomicOr(flag, 1);
}

// ---------------------------------------------------------------------------
// xproj[v] = [emb[v]@Wz[:H]+bz | emb[v]@Wr+br | emb[v]@Wh[:H]+bh], bf16 out.
// ---------------------------------------------------------------------------
template <bool F32>
__device__ void xproj_body(const void* emb, const void* Wz, const void* bz,
                           const void* Wr, const void* br, const void* Wh,
                           const void* bh, bf16* xproj, float* xe) {
  const int v = blockIdx.x, k = threadIdx.x;
  xe[k] = ldv<F32>(emb, (long)v * Hh + k);
  __syncthreads();
  float z = ldv<F32>(bz, k);
  float r = ldv<F32>(br, k);
  float h = ldv<F32>(bh, k);
  for (int i = 0; i < Hh; ++i) {
    float a = xe[i];
    z += a * ldv<F32>(Wz, (long)i * Hh + k);
    r += a * ldv<F32>(Wr, (long)i * Hh + k);
    h += a * ldv<F32>(Wh, (long)i * Hh + k);
  }
  bf16* xp = xproj + (long)v * XPS;
  xp[k]          = __float2bfloat16(z);
  xp[Hh + k]     = __float2bfloat16(r);
  xp[2 * Hh + k] = __float2bfloat16(h);
}

__global__ __launch_bounds__(512) void xproj_kernel(
    const void* emb, const void* Wz, const void* bz, const void* Wr,
    const void* br, const void* Wh, const void* bh, bf16* xproj,
    const int* __restrict__ flag) {
  __shared__ float xe[Hh];
  if (*flag)
    xproj_body<true>(emb, Wz, bz, Wr, br, Wh, bh, xproj, xe);
  else
    xproj_body<false>(emb, Wz, bz, Wr, br, Wh, bh, xproj, xe);
}

// ---------------------------------------------------------------------------
// Per-row sum_g over 4 columns: one 2-deep ushort4 Ur stream, NV neighbors.
// Per-column accumulation order: ascending i (matches scalar reference).
// ---------------------------------------------------------------------------
template <bool F32, int NV>
__device__ __forceinline__ void sumg4(const void* Ur, int c0, const float* hnc,
                                      const float* xr4, float* g) {
  float a[NV][4];
#pragma unroll
  for (int j = 0; j < NV; ++j)
#pragma unroll
    for (int c = 0; c < 4; ++c) a[j][c] = xr4[c];
  for (int i = 0; i < Hh; i += 2) {
    float w0[4], w1[4];
    ld4<F32>(Ur, (long)i * Hh + c0, w0);
    ld4<F32>(Ur, (long)(i + 1) * Hh + c0, w1);
#pragma unroll
    for (int j = 0; j < NV; ++j) {
      float h0 = hnc[j * Hh + i];
      float h1 = hnc[j * Hh + i + 1];
#pragma unroll
      for (int c = 0; c < 4; ++c) a[j][c] += h0 * w0[c];
#pragma unroll
      for (int c = 0; c < 4; ++c) a[j][c] += h1 * w1[c];
    }
  }
#pragma unroll
  for (int j = 0; j < NV; ++j)
#pragma unroll
    for (int c = 0; c < 4; ++c) g[c] += sigm(a[j][c]) * hnc[j * Hh + c0 + c];
}

// ---------------------------------------------------------------------------
// GRU scan step (xproj path): 2 rows/block, 256 threads.
// Threads 0-127 -> row 0, 128-255 -> row 1; each thread owns 4 adjacent
// columns c0 = 4*(tid&127). Weight loads are 8B ushort4 (4x bytes/instr).
// ---------------------------------------------------------------------------
template <bool F32>
__device__ void gru_body_xp(int t, const int* wid, const int* hni,
                            const bf16* xproj, const void* Wz, const void* Ur,
                            const void* Wh, bf16* hbuf, float* sh, float* sg,
                            float* hnc, int* ids, int* nvp) {
  const int tid = threadIdx.x;
  const int h = tid >> 7;        // row-half 0/1 (waves 0,1 -> 0; 2,3 -> 1)
  const int cg = tid & 127;
  const int c0 = 4 * cg;
  const int b = blockIdx.x * 2 + h;

  if (tid < 2 * MAXNB)
    ids[tid] = hni[((long)t * Bb + blockIdx.x * 2 + (tid >> 3)) * MAXNB + (tid & 7)];
  __syncthreads();
  if (cg == 0) {  // tid 0 and 128
    int n = 0;
    while (n < MAXNB && ids[h * MAXNB + n] != PADID) ++n;
    nvp[h] = n;
  }
  __syncthreads();
  const int nv = nvp[h];                 // wave-uniform
  const int* myids = ids + h * MAXNB;
  float* myhnc = hnc + h * MAXNB * Hh;
  float* mysh = sh + h * Hh;
  float* mysg = sg + h * Hh;

  const int w = wid[t * Bb + b];
  const bf16* xp = xproj + (long)w * XPS;

  float s[4] = {0.f, 0.f, 0.f, 0.f};
  for (int j = 0; j < nv; ++j) {         // wave-uniform bound
    float hv[4];
    ldh4(hbuf, (long)myids[j] * Hh + c0, hv);
#pragma unroll
    for (int c = 0; c < 4; ++c) {
      myhnc[j * Hh + c0 + c] = hv[c];
      s[c] += hv[c];
    }
  }
#pragma unroll
  for (int c = 0; c < 4; ++c) mysh[c0 + c] = s[c];
  __syncthreads();

  // z pre-activation: xz + sum_h @ Wz[H:], 4-deep ushort4 stream
  float z[4];
  ld4<F32>((const void*)xp, c0, z);  // xproj is bf16; F32 template still ok? xp always bf16
  // NOTE: xproj buffer is always bf16 — load it explicitly:
  { float tmp[4]; ldh4(xp, c0, tmp); z[0]=tmp[0]; z[1]=tmp[1]; z[2]=tmp[2]; z[3]=tmp[3]; }
  for (int i = 0; i < Hh; i += 4) {
    float wv[4][4];
#pragma unroll
    for (int u = 0; u < 4; ++u) ld4<F32>(Wz, (long)(Hh + i + u) * Hh + c0, wv[u]);
#pragma unroll
    for (int u = 0; u < 4; ++u) {
      float a = mysh[i + u];
#pragma unroll
      for (int c = 0; c < 4; ++c) z[c] += a * wv[u][c];
    }
  }

  // r gate + sum_g: single Ur stream
  float xr4[4];
  ldh4(xp, Hh + c0, xr4);
  float g[4] = {0.f, 0.f, 0.f, 0.f};
  switch (nv) {
    case 1: sumg4<F32, 1>(Ur, c0, myhnc, xr4, g); break;
    case 2: sumg4<F32, 2>(Ur, c0, myhnc, xr4, g); break;
    case 3: sumg4<F32, 3>(Ur, c0, myhnc, xr4, g); break;
    case 4: sumg4<F32, 4>(Ur, c0, myhnc, xr4, g); break;
    case 5: sumg4<F32, 5>(Ur, c0, myhnc, xr4, g); break;
    case 6: sumg4<F32, 6>(Ur, c0, myhnc, xr4, g); break;
    case 7: sumg4<F32, 7>(Ur, c0, myhnc, xr4, g); break;
    case 8: sumg4<F32, 8>(Ur, c0, myhnc, xr4, g); break;
    default: break;  // nv==0
  }
#pragma unroll
  for (int c = 0; c < 4; ++c) mysg[c0 + c] = g[c];
  __syncthreads();

  // h_tilde = tanh(xh + sum_g @ Wh[H:]), 4-deep ushort4 stream
  float ht[4];
  ldh4(xp, 2 * Hh + c0, ht);
  for (int i = 0; i < Hh; i += 4) {
    float wv[4][4];
#pragma unroll
    for (int u = 0; u < 4; ++u) ld4<F32>(Wh, (long)(Hh + i + u) * Hh + c0, wv[u]);
#pragma unroll
    for (int u = 0; u < 4; ++u) {
      float a = mysg[i + u];
#pragma unroll
      for (int c = 0; c < 4; ++c) ht[c] += a * wv[u][c];
    }
  }

  ushort4 ov;
  {
    float zz, oo;
    zz = sigm(z[0]); oo = (1.f - zz) * s[0] + zz * tanhf(ht[0]);
    bf16 t0 = __float2bfloat16(oo); ov.x = *(unsigned short*)&t0;
    zz = sigm(z[1]); oo = (1.f - zz) * s[1] + zz * tanhf(ht[1]);
    bf16 t1 = __float2bfloat16(oo); ov.y = *(unsigned short*)&t1;
    zz = sigm(z[2]); oo = (1.f - zz) * s[2] + zz * tanhf(ht[2]);
    bf16 t2 = __float2bfloat16(oo); ov.z = *(unsigned short*)&t2;
    zz = sigm(z[3]); oo = (1.f - zz) * s[3] + zz * tanhf(ht[3]);
    bf16 t3 = __float2bfloat16(oo); ov.w = *(unsigned short*)&t3;
  }
  *(ushort4*)(hbuf + ((long)t * Bb + b) * Hh + c0) = ov;
}

__global__ __launch_bounds__(256, 2) void gru_step_xp(
    int t, const int* __restrict__ wid, const int* __restrict__ hni,
    const bf16* xproj, const void* Wz, const void* Ur, const void* Wh,
    bf16* hbuf, const int* __restrict__ flag) {
  __shared__ float sh[2 * Hh];
  __shared__ float sg[2 * Hh];
  __shared__ float hnc[2 * MAXNB * Hh];
  __shared__ int   ids[2 * MAXNB];
  __shared__ int   nvp[2];
  if (*flag)
    gru_body_xp<true>(t, wid, hni, xproj, Wz, Ur, Wh, hbuf, sh, sg, hnc, ids, nvp);
  else
    gru_body_xp<false>(t, wid, hni, xproj, Wz, Ur, Wh, hbuf, sh, sg, hnc, ids, nvp);
}

// ---------------------------------------------------------------------------
// Stop head (R9-proven): rows = [emb[w] | sum(hbuf[oni]) | mol_vec]
// ---------------------------------------------------------------------------
template <bool F32>
__device__ void stop_body(const void* mol_vec, const int* wid,
                          const int* dirs, const int* oni,
                          const int* root_wid, const int* roni,
                          const void* emb, const void* U, const void* bU,
                          const void* Us, const void* bs, const bf16* hbuf,
                          float* accum,
                          float (*srow)[2 * Hh + Ll], float (*red)[256],
                          float* fin) {
  const int tid = threadIdx.x;
  const int i0 = blockIdx.x * 8;
  const int K = 2 * Hh + Ll;  // 1088

  for (int r = 0; r < 8; ++r) {
    int i = i0 + r;
    int w, b;
    const int* ids;
    if (i < TB) { w = wid[i]; b = i % Bb; ids = &oni[(long)i * MAXNB]; }
    else { int j = i - TB; w = root_wid[j]; b = j; ids = &roni[(long)j * MAXNB]; }
    for (int c = tid; c < K; c += 256) {
      float v;
      if (c < Hh) v = ldv<F32>(emb, (long)w * Hh + c);
      else if (c < 2 * Hh) {
        int cc = c - Hh;
        float s = 0.f;
        for (int j = 0; j < MAXNB; ++j) s += b2f(hbuf[(long)ids[j] * Hh + cc]);
        v = s;
      } else v = ldv<F32>(mol_vec, (long)b * Ll + (c - 2 * Hh));
      srow[r][c] = v;
    }
  }
  __syncthreads();

  const int k0 = tid, k1 = tid + 256;
  float acc[8][2] = {};
  for (int kk = 0; kk < K; kk += 4) {
    float u0[4], u1[4];
#pragma unroll
    for (int u = 0; u < 4; ++u) {
      u0[u] = ldv<F32>(U, (long)(kk + u) * Hh + k0);
      u1[u] = ldv<F32>(U, (long)(kk + u) * Hh + k1);
    }
#pragma unroll
    for (int u = 0; u < 4; ++u) {
#pragma unroll
      for (int r = 0; r < 8; ++r) {
        float a = srow[r][kk + u];
        acc[r][0] += a * u0[u]; acc[r][1] += a * u1[u];
      }
    }
  }
  float bU0 = ldv<F32>(bU, k0), bU1 = ldv<F32>(bU, k1);
  float us0 = ldv<F32>(Us, k0), us1 = ldv<F32>(Us, k1);
  __syncthreads();
#pragma unroll
  for (int r = 0; r < 8; ++r)
    red[r][tid] = fmaxf(acc[r][0] + bU0, 0.f) * us0 + fmaxf(acc[r][1] + bU1, 0.f) * us1;
  __syncthreads();
  for (int off = 128; off; off >>= 1) {
    if (tid < off) {
#pragma unroll
      for (int r = 0; r < 8; ++r) red[r][tid] += red[r][tid + off];
    }
    __syncthreads();
  }
  if (tid < 8) {
    int i = i0 + tid;
    float s = red[tid][0] + ldv<F32>(bs, 0);
    float tgt = (i < TB) ? (float)dirs[i] : 0.f;
    float loss = fmaxf(s, 0.f) - s * tgt + log1pf(expf(-fabsf(s)));
    float ok = ((s >= 0.5f) == (tgt > 0.5f)) ? 1.f : 0.f;
    fin[tid] = loss; fin[8 + tid] = ok;
  }
  __syncthreads();
  if (tid == 0) {
    float ls = 0.f, oks = 0.f;
    for (int r = 0; r < 8; ++r) { ls += fin[r]; oks += fin[8 + r]; }
    atomicAdd(&accum[0], ls);
    atomicAdd(&accum[1], oks);
  }
}

__global__ __launch_bounds__(256) void stop_kernel(
    const void* mol_vec, const int* __restrict__ wid,
    const int* __restrict__ dirs, const int* __restrict__ oni,
    const int* __restrict__ root_wid, const int* __restrict__ roni,
    const void* emb, const void* U, const void* bU, const void* Us,
    const void* bs, const bf16* hbuf, float* accum,
    const int* __restrict__ flag) {
  __shared__ float srow[8][2 * Hh + Ll];
  __shared__ float red[8][256];
  __shared__ float fin[16];
  if (*flag)
    stop_body<true>(mol_vec, wid, dirs, oni, root_wid, roni, emb, U, bU, Us,
                    bs, hbuf, accum, srow, red, fin);
  else
    stop_body<false>(mol_vec, wid, dirs, oni, root_wid, roni, emb, U, bU, Us,
                     bs, hbuf, accum, srow, red, fin);
}

// ---------------------------------------------------------------------------
// Pred head (R9-proven): hid = relu([pred_h | mv] @ W + bW); logits = hid @ Wo
// ---------------------------------------------------------------------------
template <bool F32>
__device__ void pred_body(const void* mol_vec, const int* y_wid,
                          const int* dirs, const int* root_wid, const void* W,
                          const void* bW, const void* Wo, const void* bo,
                          const bf16* hbuf, float* accum,
                          float (*srow)[Hh + Ll], float (*hid)[Hh],
                          float* rv, int* ri, float* sb) {
  const int tid = threadIdx.x;
  const int i0 = blockIdx.x * 8;
  const int K1 = Hh + Ll;  // 576

  for (int r = 0; r < 8; ++r) {
    int i = i0 + r;
    int b = (i < Bb) ? i : (i - Bb) % Bb;
    for (int c = tid; c < K1; c += 256) {
      float v;
      if (c < Hh) v = (i < Bb) ? 0.f : b2f(hbuf[(long)(i - Bb) * Hh + c]);
      else v = ldv<F32>(mol_vec, (long)b * Ll + (c - Hh));
      srow[r][c] = v;
    }
  }
  __syncthreads();

  const int k0 = tid, k1 = tid + 256;
  float acc[8][2] = {};
  for (int kk = 0; kk < K1; kk += 4) {
    float w0[4], w1[4];
#pragma unroll
    for (int u = 0; u < 4; ++u) {
      w0[u] = ldv<F32>(W, (long)(kk + u) * Hh + k0);
      w1[u] = ldv<F32>(W, (long)(kk + u) * Hh + k1);
    }
#pragma unroll
    for (int u = 0; u < 4; ++u) {
#pragma unroll
      for (int r = 0; r < 8; ++r) {
        float a = srow[r][kk + u];
        acc[r][0] += a * w0[u]; acc[r][1] += a * w1[u];
      }
    }
  }
  float bW0 = ldv<F32>(bW, k0), bW1 = ldv<F32>(bW, k1);
#pragma unroll
  for (int r = 0; r < 8; ++r) {
    hid[r][k0] = fmaxf(acc[r][0] + bW0, 0.f);
    hid[r][k1] = fmaxf(acc[r][1] + bW1, 0.f);
  }
  __syncthreads();

  float lg[8][4] = {};
  for (int kk = 0; kk < Hh; kk += 2) {
    float wa[2][4];
#pragma unroll
    for (int u = 0; u < 2; ++u) {
      wa[u][0] = ldv<F32>(Wo, (long)(kk + u) * Vv + tid);
      wa[u][1] = ldv<F32>(Wo, (long)(kk + u) * Vv + tid + 256);
      wa[u][2] = ldv<F32>(Wo, (long)(kk + u) * Vv + tid + 512);
      wa[u][3] = ldv<F32>(Wo, (long)(kk + u) * Vv + tid + 768);
    }
#pragma unroll
    for (int u = 0; u < 2; ++u) {
#pragma unroll
      for (int r = 0; r < 8; ++r) {
        float a = hid[r][kk + u];
        lg[r][0] += a * wa[u][0]; lg[r][1] += a * wa[u][1];
        lg[r][2] += a * wa[u][2]; lg[r][3] += a * wa[u][3];
      }
    }
  }
  float bo0 = ldv<F32>(bo, tid);
  float bo1 = ldv<F32>(bo, tid + 256);
  float bo2 = ldv<F32>(bo, tid + 512);
  float bo3 = ldv<F32>(bo, tid + 768);

  float plloss = 0.f, pnum = 0.f, pmask = 0.f;  // live in thread 0
  for (int r = 0; r < 8; ++r) {
    int i = i0 + r;
    int tgt = (i < Bb) ? root_wid[i] : y_wid[i - Bb];
    float msk = (i < Bb) ? 1.f : (float)dirs[i - Bb];
    float v0 = lg[r][0] + bo0, v1 = lg[r][1] + bo1;
    float v2 = lg[r][2] + bo2, v3 = lg[r][3] + bo3;

    float bm = v0; int bi = tid;
    if (v1 > bm) { bm = v1; bi = tid + 256; }
    if (v2 > bm) { bm = v2; bi = tid + 512; }
    if (v3 > bm) { bm = v3; bi = tid + 768; }
    rv[tid] = bm; ri[tid] = bi;
    if ((tgt & 255) == tid) {
      int cc = tgt >> 8;
      sb[0] = (cc == 0) ? v0 : (cc == 1) ? v1 : (cc == 2) ? v2 : v3;
    }
    __syncthreads();
    for (int off = 128; off; off >>= 1) {
      if (tid < off) {
        float o = rv[tid + off]; int oi = ri[tid + off];
        if (o > rv[tid] || (o == rv[tid] && oi < ri[tid])) { rv[tid] = o; ri[tid] = oi; }
      }
      __syncthreads();
    }
    float m = rv[0];
    int am = ri[0];
    __syncthreads();
    rv[tid] = __expf(v0 - m) + __expf(v1 - m) + __expf(v2 - m) + __expf(v3 - m);
    __syncthreads();
    for (int off = 128; off; off >>= 1) {
      if (tid < off) rv[tid] += rv[tid + off];
      __syncthreads();
    }
    if (tid == 0) {
      float lse = m + __logf(rv[0]);
      float ce = lse - sb[0];
      plloss += ce * msk;
      pnum += (am == tgt) ? msk : 0.f;
      pmask += msk;
    }
    __syncthreads();
  }
  if (tid == 0) {
    atomicAdd(&accum[2], plloss);
    atomicAdd(&accum[3], pnum);
    atomicAdd(&accum[4], pmask);
  }
}

__global__ __launch_bounds__(256) void pred_kernel(
    const void* mol_vec, const int* __restrict__ y_wid,
    const int* __restrict__ dirs, const int* __restrict__ root_wid,
    const void* W, const void* bW, const void* Wo, const void* bo,
    const bf16* hbuf, float* accum, const int* __restrict__ flag) {
  __shared__ float srow[8][Hh + Ll];
  __shared__ float hid[8][Hh];
  __shared__ float rv[256];
  __shared__ int   ri[256];
  __shared__ float sb[2];
  if (*flag)
    pred_body<true>(mol_vec, y_wid, dirs, root_wid, W, bW, Wo, bo, hbuf,
                    accum, srow, hid, rv, ri, sb);
  else
    pred_body<false>(mol_vec, y_wid, dirs, root_wid, W, bW, Wo, bo, hbuf,
                     accum, srow, hid, rv, ri, sb);
}

__global__ void finalize_kernel(const float* __restrict__ accum,
                                const int* __restrict__ flag, void* out) {
  if (threadIdx.x == 0 && blockIdx.x == 0) {
    float o0 = accum[2] / (float)Bb;      // pred_loss
    float o1 = accum[0] / (float)Bb;      // stop_loss
    float o2 = accum[3] / accum[4];       // pred_acc
    float o3 = accum[1] / (float)NROWS;   // stop_acc
    if (*flag) {
      float* o = (float*)out;
      o[0] = o0; o[1] = o1; o[2] = o2; o[3] = o3;
    } else {
      bf16* o = (bf16*)out;
      o[0] = __float2bfloat16(o0); o[1] = __float2bfloat16(o1);
      o[2] = __float2bfloat16(o2); o[3] = __float2bfloat16(o3);
    }
  }
}

extern "C" void kernel_launch(void* const* d_in, const int* in_sizes, int n_in,
                              void* d_out, int out_size, void* d_ws, size_t ws_size,
                              hipStream_t stream) {
  const void* mol_vec  = d_in[0];
  const int*  wid      = (const int*)d_in[1];
  const int*  y_wid    = (const int*)d_in[2];
  const int*  dirs     = (const int*)d_in[3];
  const int*  hni      = (const int*)d_in[4];
  const int*  oni      = (const int*)d_in[5];
  const int*  root_wid = (const int*)d_in[6];
  const int*  roni     = (const int*)d_in[7];
  const void* emb      = d_in[8];
  const void* Wz       = d_in[9];
  const void* bz       = d_in[10];
  const void* Wr       = d_in[11];
  const void* br       = d_in[12];
  const void* Ur       = d_in[13];
  const void* Wh       = d_in[14];
  const void* bh       = d_in[15];
  const void* W        = d_in[16];
  const void* bW       = d_in[17];
  const void* U        = d_in[18];
  const void* bU       = d_in[19];
  const void* Wo       = d_in[20];
  const void* bo       = d_in[21];
  const void* Us       = d_in[22];
  const void* bs       = d_in[23];

  // ws layout: [accum 8f][flag 1i][pad->64B][hbuf (TB+1)*Hh bf16][xproj V*XPS bf16]
  float* accum = (float*)d_ws;
  int*   flag  = (int*)d_ws + 8;
  bf16*  hbuf  = (bf16*)((char*)d_ws + 64);
  bf16*  xproj = hbuf + (long)(TB + 1) * Hh;

  hipMemsetAsync(d_ws, 0, 64, stream);                                   // accum+flag
  hipMemsetAsync(hbuf + (long)TB * Hh, 0, Hh * sizeof(bf16), stream);    // PAD row

  detect_kernel<<<64, 256, 0, stream>>>((const unsigned short*)emb, flag);

  xproj_kernel<<<Vv, 512, 0, stream>>>(emb, Wz, bz, Wr, br, Wh, bh, xproj, flag);
  for (int t = 0; t < Tt; ++t) {
    gru_step_xp<<<Bb / 2, 256, 0, stream>>>(t, wid, hni, xproj, Wz, Ur, Wh,
                                            hbuf, flag);
  }
  stop_kernel<<<NROWS / 8, 256, 0, stream>>>(mol_vec, wid, dirs, oni, root_wid,
                                             roni, emb, U, bU, Us, bs, hbuf,
                                             accum, flag);
  pred_kernel<<<NROWS / 8, 256, 0, stream>>>(mol_vec, y_wid, dirs, root_wid, W,
                                             bW, Wo, bo, hbuf, accum, flag);
  finalize_kernel<<<1, 64, 0, stream>>>(accum, flag, d_out);
}